// Round 6
// baseline (64.086 us; speedup 1.0000x reference)
//
#include <hip/hip_runtime.h>
#include <hip/hip_bf16.h>

using bf16x8 = __attribute__((ext_vector_type(8))) short;
using f32x4  = __attribute__((ext_vector_type(4))) float;
using f32x2  = __attribute__((ext_vector_type(2))) float;

__device__ __forceinline__ unsigned short f2bf(float x) {
    unsigned int u = __float_as_uint(x);
    return (unsigned short)((u + 0x7FFFu + ((u >> 16) & 1u)) >> 16);
}

// -------------------------------------------------------------------------
// K0: pack text_embeddings [91][512] f32 -> [96][512] bf16 (rows 91..95 = 0)
// -------------------------------------------------------------------------
__global__ __launch_bounds__(256)
void k_prep(const float* __restrict__ te, unsigned short* __restrict__ te_bf) {
    const int r = blockIdx.x;            // 0..95
    for (int i = threadIdx.x; i < 512; i += 256) {
        const float v = (r < 91) ? te[(size_t)r * 512 + i] : 0.f;
        te_bf[(size_t)r * 512 + i] = f2bf(v);
    }
}

// -------------------------------------------------------------------------
// K1: ccombo[n][c] = focal(logits[n][c]) + 0.5*(1 - <v_norm[n], te[c]>)
// grid 1024, block 256 = 16 rows, 4 waves K-split (128 k each).
// -------------------------------------------------------------------------
__global__ __launch_bounds__(256)
void k_class_embed(const float* __restrict__ logits,       // [16384][91]
                   const float* __restrict__ embed,        // [16384][512]
                   const unsigned short* __restrict__ te_bf, // [96][512] bf16
                   float* __restrict__ ccombo)             // [16384][96]
{
    __shared__ float accs[4][16 * 96];     // 24576 B
    __shared__ float sq_s[4][16];

    const int tid  = threadIdx.x;
    const int lane = tid & 63;
    const int wv   = tid >> 6;             // K-chunk 0..3
    const int r16  = lane & 15;
    const int q    = lane >> 4;
    const int n0   = blockIdx.x * 16;

    f32x4 acc[6];
#pragma unroll
    for (int j = 0; j < 6; ++j) acc[j] = (f32x4){0.f, 0.f, 0.f, 0.f};
    float sumsq = 0.f;

    const float* arow = embed + (size_t)(n0 + r16) * 512 + wv * 128 + q * 8;
#pragma unroll
    for (int ks = 0; ks < 4; ++ks) {
        const float4 a0 = *(const float4*)(arow + ks * 32);
        const float4 a1 = *(const float4*)(arow + ks * 32 + 4);
        const float fv[8] = {a0.x, a0.y, a0.z, a0.w, a1.x, a1.y, a1.z, a1.w};
        bf16x8 af;
#pragma unroll
        for (int j = 0; j < 8; ++j) {
            sumsq += fv[j] * fv[j];
            af[j] = (short)f2bf(fv[j]);
        }
#pragma unroll
        for (int ct = 0; ct < 6; ++ct) {
            const bf16x8 bfr = *(const bf16x8*)(te_bf + (size_t)(ct * 16 + r16) * 512
                                                + wv * 128 + ks * 32 + q * 8);
            acc[ct] = __builtin_amdgcn_mfma_f32_16x16x32_bf16(af, bfr, acc[ct], 0, 0, 0);
        }
    }
    sumsq += __shfl_xor(sumsq, 16);
    sumsq += __shfl_xor(sumsq, 32);
    if (lane < 16) sq_s[wv][r16] = sumsq;

#pragma unroll
    for (int ct = 0; ct < 6; ++ct)
#pragma unroll
        for (int j = 0; j < 4; ++j)
            accs[wv][(q * 4 + j) * 96 + ct * 16 + r16] = acc[ct][j];
    __syncthreads();

#pragma unroll
    for (int i = 0; i < 6; ++i) {
        const int e = tid + i * 256;                 // < 1536
        const int row = e / 96, col = e - row * 96;
        float v = 0.f;
        if (col < 91) {
            const float dot = accs[0][e] + accs[1][e] + accs[2][e] + accs[3][e];
            const float rn  = rsqrtf(sq_s[0][row] + sq_s[1][row] + sq_s[2][row] + sq_s[3][row]);
            const float x = logits[(size_t)(n0 + row) * 91 + col];
            const float p = 1.f / (1.f + __expf(-x));
            const float pos = 0.25f * (1.f - p) * (1.f - p) * (-__logf(p + 1e-8f));
            const float neg = 0.75f * p * p * (-__logf(1.f - p + 1e-8f));
            v = (pos - neg) + 0.5f - 0.5f * dot * rn;
        }
        ccombo[(size_t)n0 * 96 + e] = v;
    }
}

// -------------------------------------------------------------------------
// K2: out[n][m] = ccombo[n][id[m]] + L1 - GIoU
// grid 512 n-chunks x 13 m-chunks; block 256 = 32 n x 128 m.
// Wave handles rows pass*4+wv (wave-uniform) -> pbox via scalar loads;
// each lane owns 2 m-boxes in registers. LDS = cc_s only (12.3 KB).
// -------------------------------------------------------------------------
__global__ __launch_bounds__(256, 8)
void k_cost(const float* __restrict__ pboxes,   // [16384][4] cxcywh
            const float* __restrict__ tboxes,   // [1600][4]  cxcywh
            const int*   __restrict__ tids,     // [1600]
            const float* __restrict__ ccombo,   // [16384][96]
            float* __restrict__ out)            // [16384][1600]
{
    __shared__ float cc_s[32 * 96];   // 12288 B

    const int tid    = threadIdx.x;
    const int bx     = blockIdx.x;
    const int mchunk = bx % 13;               // 13 chunks of 128 m
    const int nchunk = bx / 13;               // 512 chunks of 32 n
    const int n0     = nchunk * 32;

    // stage cc rows [n0, n0+32): 3072 floats = 768 float4 = 3 per thread
    {
        const f32x4* src = (const f32x4*)(ccombo + (size_t)n0 * 96);
        f32x4* dst = (f32x4*)cc_s;
#pragma unroll
        for (int i = 0; i < 3; ++i) dst[tid + i * 256] = src[tid + i * 256];
    }

    // ---- per-thread m-group of 2 in registers
    const int lane = tid & 63;
    const int wv   = tid >> 6;                         // wave id 0..3
    const int m    = mchunk * 128 + lane * 2;          // 0..1662, even
    const int mr   = (m < 1600) ? m : 1598;            // clamp for safe loads
    float tcx[2], tcy[2], tw[2], th[2];
    float tx0[2], ty0[2], tx1[2], ty1[2], ta[2];
#pragma unroll
    for (int j = 0; j < 2; ++j) {
        const float4 b = *(const float4*)(tboxes + (size_t)(mr + j) * 4);
        tcx[j] = b.x; tcy[j] = b.y; tw[j] = b.z; th[j] = b.w;
        tx0[j] = __builtin_fmaf(-0.5f, b.z, b.x);
        ty0[j] = __builtin_fmaf(-0.5f, b.w, b.y);
        tx1[j] = __builtin_fmaf( 0.5f, b.z, b.x);
        ty1[j] = __builtin_fmaf( 0.5f, b.w, b.y);
        ta[j]  = b.z * b.w;
    }
    const int2 idv = *(const int2*)(tids + mr);
    const int ids[2] = {idv.x, idv.y};
    __syncthreads();

    const bool do_store = (m < 1600);

#pragma unroll
    for (int pass = 0; pass < 8; ++pass) {
        const int nl  = pass * 4 + wv;                           // wave-uniform
        const int nlu = __builtin_amdgcn_readfirstlane(nl);      // pin to SGPR
        const float4 PB = *(const float4*)(pboxes + (size_t)(n0 + nlu) * 4); // s_load
        const float pcx = PB.x, pcy = PB.y, pw = PB.z, ph = PB.w;
        const float px0 = __builtin_fmaf(-0.5f, pw, pcx);
        const float py0 = __builtin_fmaf(-0.5f, ph, pcy);
        const float px1 = __builtin_fmaf( 0.5f, pw, pcx);
        const float py1 = __builtin_fmaf( 0.5f, ph, pcy);
        const float pa  = pw * ph;
        const float* ccrow = &cc_s[nl * 96];
        float res[2];
#pragma unroll
        for (int j = 0; j < 2; ++j) {
            // intersection extents (unclamped)
            const float dx = fminf(px1, tx1[j]) - fmaxf(px0, tx0[j]);
            const float dy = fminf(py1, ty1[j]) - fmaxf(py0, ty0[j]);
            const float iw = fmaxf(dx, 0.f), ih = fmaxf(dy, 0.f);
            const float inter = iw * ih;
            // enclosing box via sum identity (no extra min/max)
            const float ew = (pw + tw[j]) - dx;
            const float eh = (ph + th[j]) - dy;
            const float ae = ew * eh;
            const float uni = __builtin_fmaf(-iw, ih, pa + ta[j]);
            const float l1 = fabsf(pcx - tcx[j]) + fabsf(pcy - tcy[j])
                           + fabsf(pw - tw[j])  + fabsf(ph - th[j]);
            const float aemu = ae - uni;
            const float num = __builtin_fmaf(inter, ae, -(uni * aemu));
            const float g   = __fdividef(num, uni * ae);
            res[j] = (ccrow[ids[j]] + l1) - g;
        }
        if (do_store) {
            f32x2 r2 = {res[0], res[1]};
            __builtin_nontemporal_store(r2,
                (f32x2*)(out + (size_t)(n0 + nl) * 1600 + m));
        }
    }
}

extern "C" void kernel_launch(void* const* d_in, const int* in_sizes, int n_in,
                              void* d_out, int out_size, void* d_ws, size_t ws_size,
                              hipStream_t stream) {
    const float* pred_logits = (const float*)d_in[0];   // [16,1024,91]
    const float* pred_boxes  = (const float*)d_in[1];   // [16,1024,4]
    const float* pred_embed  = (const float*)d_in[2];   // [16,1024,512]
    const float* text_emb    = (const float*)d_in[3];   // [91,512]
    const int*   tgt_ids     = (const int*)d_in[4];     // [1600]
    const float* tgt_bbox    = (const float*)d_in[5];   // [1600,4]
    float* out = (float*)d_out;                         // [16384,1600]

    unsigned short* te_bf = (unsigned short*)d_ws;                    // 96*512*2 = 96 KB
    float* ccombo = (float*)((char*)d_ws + 102400);                   // 16384*96*4 = 6.29 MB

    k_prep<<<96, 256, 0, stream>>>(text_emb, te_bf);
    k_class_embed<<<1024, 256, 0, stream>>>(pred_logits, pred_embed, te_bf, ccombo);
    k_cost<<<512 * 13, 256, 0, stream>>>(pred_boxes, tgt_bbox, tgt_ids, ccombo, out);
}